// Round 5
// baseline (112.188 us; speedup 1.0000x reference)
//
#include <hip/hip_runtime.h>
#include <hip/hip_bf16.h>

#define BATCH 16384
#define DIM   512
#define UNITS 1024
// GAMMA = 0.5 folded into epilogue: out = exp(cross - 0.5*xsq - 0.5*musq)

typedef float v16f __attribute__((ext_vector_type(16)));

#define MFMA_F8(a, b, c) __builtin_amdgcn_mfma_f32_32x32x16_fp8_fp8((a), (b), (c), 0, 0, 0)

__device__ __forceinline__ void async_copy16(const void* g, void* l) {
    __builtin_amdgcn_global_load_lds(
        (const __attribute__((address_space(1))) void*)g,
        (__attribute__((address_space(3))) void*)l,
        16 /*bytes*/, 0 /*offset*/, 0 /*aux*/);
}

static __device__ __forceinline__ int2 cvt8(const float4 f0, const float4 f1) {
    int lo = __builtin_amdgcn_cvt_pk_fp8_f32(f0.x, f0.y, 0, false);
    lo     = __builtin_amdgcn_cvt_pk_fp8_f32(f0.z, f0.w, lo, true);
    int hi = __builtin_amdgcn_cvt_pk_fp8_f32(f1.x, f1.y, 0, false);
    hi     = __builtin_amdgcn_cvt_pk_fp8_f32(f1.z, f1.w, hi, true);
    return make_int2(lo, hi);
}
static __device__ __forceinline__ float dot8(const float4 f0, const float4 f1) {
    return f0.x * f0.x + f0.y * f0.y + f0.z * f0.z + f0.w * f0.w
         + f1.x * f1.x + f1.y * f1.y + f1.z * f1.z + f1.w * f1.w;
}

// Fragment-order prep v3 (fp8 e4m3), xsq/musq on ORIGINAL fp32 values.
// Same layouts as before:
// A8f: byte ((chunk*32 + kw)*64 + lane)*8 — lane l holds
//   A[chunk*32 + (l&31)][kw*16 + (l>>5)*8 + 0..7].
// B8f: byte ((ng*32 + kw)*64 + lane)*8 — lane l holds
//   B[kw*16 + (l>>5)*8 + 0..7][ng*32 + (l&31)].
// v3 change: both paths run in TWO half-stages so LDS <= 37 KB ->
// 4 blocks/CU -> all 544 blocks co-resident in ONE dispatch round
// (was 68 KB -> 2/CU -> 2.1 serialized rounds).
// Blocks 0..31: B path. Blocks 32..543: A path, chunk c = ((b-32)&7)*64
// + ((b-32)>>3): chunk c converted on XCD floor(c/64), matching the GEMM
// blocks that read it (L2-local).
__global__ __launch_bounds__(256, 4)
void prep_kernel(const float* __restrict__ in, const float* __restrict__ mu,
                 unsigned char* __restrict__ A8f, unsigned char* __restrict__ B8f,
                 float* __restrict__ xsq, float* __restrict__ musq) {
    __shared__ __attribute__((aligned(16))) char smem[37120];
    const int t  = threadIdx.x;
    const int l  = t & 63;
    const int ln = l & 31, h = l >> 5;

    if (blockIdx.x >= UNITS / 32) {
        // ---- A path: one block per 32-row chunk, two 16-row stages ----
        float* lds = (float*)smem;                    // [16][516]
        float* red = (float*)(smem + 16 * 516 * 4);   // [16][64] xsq partials
        const int bb = blockIdx.x - UNITS / 32;
        const int c  = (bb & 7) * 64 + (bb >> 3);     // chunk 0..511
        const float4* src = (const float4*)(in + (size_t)c * 32 * DIM);
        const int kw  = t >> 3;                       // 0..31
        const int sub = t & 7;
        const int hh  = sub & 1;                      // k-half
        const int rq  = sub >> 1;                     // row quad 0..3
        float4* l4 = (float4*)lds;

#pragma unroll
        for (int s = 0; s < 2; s++) {
            // load rows [s*16, s*16+16): 2048 float4, coalesced
#pragma unroll
            for (int i = 0; i < 8; i++) {
                const int f = i * 256 + t;            // 0..2047
                l4[(f >> 7) * 129 + (f & 127)] = src[s * 2048 + f];
            }
            __syncthreads();
            // convert: thread covers (kw, hh) x 4 rows
#pragma unroll
            for (int i = 0; i < 4; i++) {
                const int rloc = rq * 4 + i;          // row-in-stage 0..15
                const float* p = lds + rloc * 516 + kw * 16 + hh * 8;
                float4 f0 = *(const float4*)p;
                float4 f1 = *(const float4*)(p + 4);
                red[rloc * 64 + kw * 2 + hh] = dot8(f0, f1);
                *(int2*)(A8f + (((size_t)c * 32 + kw) * 64
                                + hh * 32 + s * 16 + rloc) * 8) = cvt8(f0, f1);
            }
            __syncthreads();                          // lds+red complete
            if (t < 16) {
                float a = 0.f;
#pragma unroll
                for (int i2 = 0; i2 < 64; i2++) a += red[t * 64 + i2];
                xsq[c * 32 + s * 16 + t] = a;
            }
            // stage-1 load writes lds main (not red); next barrier (post-load)
            // orders the t<16 red reads before stage-1 convert's red writes.
        }
    } else {
        // ---- B path: one block per 32-col group, two 256-k stages ----
        float* lds = (float*)smem;                    // [256][33]
        float* red = (float*)(smem + 256 * 33 * 4);   // [32][8] musq partials
        const int nb  = blockIdx.x;
        const int n0b = nb * 32;
        const int col = t & 31, kg = t >> 5;
        const int wv  = t >> 6;                       // 0..3
        float s2 = 0.f;

#pragma unroll
        for (int s = 0; s < 2; s++) {
            // load k in [s*256, s*256+256): 32-lane rows of 128 B
#pragma unroll 4
            for (int i = 0; i < 32; i++) {
                const int kk = i * 8 + kg;            // 0..255
                float v = mu[(size_t)(s * 256 + kk) * UNITS + n0b + col];
                s2 += v * v;
                lds[kk * 33 + col] = v;
            }
            __syncthreads();
            // convert kw_loc in [0,16): wave wv covers 4 kws
#pragma unroll
            for (int jj = 0; jj < 4; jj++) {
                const int kwl = wv * 4 + jj;
                const int kwg = s * 16 + kwl;
                const float* p = lds + (kwl * 16 + h * 8) * 33 + ln;
                float f[8];
#pragma unroll
                for (int i = 0; i < 8; i++) f[i] = p[i * 33];
                *(int2*)(B8f + (((size_t)nb * 32 + kwg) * 64 + l) * 8) =
                    cvt8(make_float4(f[0], f[1], f[2], f[3]),
                         make_float4(f[4], f[5], f[6], f[7]));
            }
            __syncthreads();
        }
        red[col * 8 + kg] = s2;
        __syncthreads();
        if (t < 32) {
            float a = 0.f;
#pragma unroll
            for (int i = 0; i < 8; i++) a += red[t * 8 + i];
            musq[n0b + t] = a;
        }
    }
}

// RBF GEMM (unchanged from R4): 512 blocks x 512 threads (8 waves),
// 2 blocks/CU (64 KB LDS). Block tile 256M x 128N. Grid: xcd=b&7, j=b>>3,
// mt=xcd*8+(j&7), nt=j>>3; the 8 n-blocks of an m-tile sit on one XCD
// (L2-local A8f, matches prep placement); co-resident pair (b, b+256)
// shares the same m-tile. Wave tile 64M x 64N as TWO 32M x 64N passes:
// K-loop + store epilogue per pass (pass-0 stores overlap pass-1 compute;
// no barriers after the B stage).
__global__ __launch_bounds__(512, 4)
void rbf_gemm_kernel(const unsigned char* __restrict__ A8f,
                     const unsigned char* __restrict__ B8f,
                     const float* __restrict__ xsq,
                     const float* __restrict__ musq,
                     float* __restrict__ out) {
    __shared__ __attribute__((aligned(16))) unsigned char Bs[65536]; // 64 KB

    const int t  = threadIdx.x;
    const int l  = t & 63;
    const int w  = t >> 6;          // wave 0..7
    const int ln = l & 31;
    const int h  = l >> 5;

    const int b   = blockIdx.x;     // 0..511
    const int xcd = b & 7;
    const int j   = b >> 3;         // 0..63
    const int m0  = (xcd * 8 + (j & 7)) * 256;
    const int n0  = (j >> 3) * 128;
    const int wm  = (w >> 1) * 64;  // wave row origin in tile (4 m-groups)
    const int wn  = (w & 1) * 64;   // wave col origin in tile (2 n-groups)

    // ---- Stage B-tile (contiguous 64 KB slice of B8f) into LDS ----
    const unsigned char* bsrc = B8f + (size_t)n0 * 512;  // nt*4 ng * 16384 B
#pragma unroll
    for (int i = 0; i < 8; i++) {
        const int c = i * 512 + t;                       // 16B chunk 0..4095
        async_copy16(bsrc + c * 16, Bs + c * 16);
    }
    __syncthreads();                                     // only barrier

    const long* BsL = (const long*)Bs;
    const long* Bp  = BsL + (size_t)(wn >> 5) * 2048 + l;

    // ---- Two M-passes: 32-row K-loop then immediate store epilogue ----
#pragma unroll
    for (int p = 0; p < 2; p++) {
        const int mbase = m0 + wm + p * 32;
        const long* Af = (const long*)A8f + (size_t)(mbase >> 5) * 2048 + l;

        v16f acc0 = (v16f)0.f, acc1 = (v16f)0.f;
#pragma unroll 4
        for (int kw = 0; kw < 32; kw++) {
            long a  = Af[kw * 64];
            long b0 = Bp[kw * 64];
            long b1 = Bp[2048 + kw * 64];
            acc0 = MFMA_F8(a, b0, acc0);
            acc1 = MFMA_F8(a, b1, acc1);
        }

        // Epilogue for rows [mbase, mbase+32). C/D layout: col = l&31,
        // row = (r&3) + 8*(r>>2) + 4*(l>>5).
        const float xv  = -0.5f * xsq[mbase + ln];       // lane ln: row mbase+ln
        const float mb0 = -0.5f * musq[n0 + wn + ln];
        const float mb1 = -0.5f * musq[n0 + wn + 32 + ln];
        float* obase = out + n0 + wn + ln;
#pragma unroll
        for (int r = 0; r < 16; r++) {
            const int rl = (r & 3) + 8 * (r >> 2) + 4 * h;
            const float xb = __shfl(xv, rl, 64);
            float* orow = obase + (size_t)(mbase + rl) * UNITS;
            __builtin_nontemporal_store(__expf(acc0[r] + xb + mb0), orow);
            __builtin_nontemporal_store(__expf(acc1[r] + xb + mb1), orow + 32);
        }
    }
}

extern "C" void kernel_launch(void* const* d_in, const int* in_sizes, int n_in,
                              void* d_out, int out_size, void* d_ws, size_t ws_size,
                              hipStream_t stream) {
    const float* inputs = (const float*)d_in[0];   // [16384, 512] fp32
    const float* mu     = (const float*)d_in[1];   // [512, 1024] fp32
    float* out = (float*)d_out;                    // [16384, 1024] fp32

    char* ws = (char*)d_ws;
    unsigned char* A8f = (unsigned char*)ws;                           // 8 MiB
    unsigned char* B8f = (unsigned char*)(ws + (size_t)BATCH * DIM);   // 512 KiB
    float* xsq  = (float*)(ws + (size_t)BATCH * DIM + (size_t)UNITS * DIM);
    float* musq = xsq + BATCH;

    prep_kernel<<<UNITS / 32 + BATCH / 32, 256, 0, stream>>>(
        inputs, mu, A8f, B8f, xsq, musq);
    rbf_gemm_kernel<<<512, 512, 0, stream>>>(A8f, B8f, xsq, musq, out);
}

// Round 6
// 109.112 us; speedup vs baseline: 1.0282x; 1.0282x over previous
//
#include <hip/hip_runtime.h>
#include <hip/hip_bf16.h>

#define BATCH 16384
#define DIM   512
#define UNITS 1024
// GAMMA = 0.5 folded into epilogue: out = exp(cross - 0.5*xsq - 0.5*musq)

typedef float v16f __attribute__((ext_vector_type(16)));

#define APITCH 516   // fp32 LDS pitch (floats) for prep-A transpose reads
#define BPITCH 33

#define MFMA_F8(a, b, c) __builtin_amdgcn_mfma_f32_32x32x16_fp8_fp8((a), (b), (c), 0, 0, 0)

__device__ __forceinline__ void async_copy16(const void* g, void* l) {
    __builtin_amdgcn_global_load_lds(
        (const __attribute__((address_space(1))) void*)g,
        (__attribute__((address_space(3))) void*)l,
        16 /*bytes*/, 0 /*offset*/, 0 /*aux*/);
}

// Fragment-order prep (fp8 e4m3) — identical to R4 (best measured variant).
// A8f: byte ((chunk*32 + kw)*64 + lane)*8 — lane l holds
//   A[chunk*32 + (l&31)][kw*16 + (l>>5)*8 + 0..7].
// B8f: byte ((ng*32 + kw)*64 + lane)*8 — lane l holds
//   B[kw*16 + (l>>5)*8 + 0..7][ng*32 + (l&31)].
// Blocks 0..31: B path. Blocks 32..543: A path, chunk c = ((b-32)&7)*64 +
// ((b-32)>>3) so chunk c is converted on XCD floor(c/64) — the same XCD
// whose GEMM blocks read it (L2-local).
__global__ __launch_bounds__(256)
void prep_kernel(const float* __restrict__ in, const float* __restrict__ mu,
                 unsigned char* __restrict__ A8f, unsigned char* __restrict__ B8f,
                 float* __restrict__ xsq, float* __restrict__ musq) {
    __shared__ __attribute__((aligned(16))) char smem[512 * BPITCH * 4 + 1024];
    const int t  = threadIdx.x;
    const int l  = t & 63, w = t >> 6;
    const int ln = l & 31, h = l >> 5;

    if (blockIdx.x >= UNITS / 32) {
        // ---- A path: one block per 32-row chunk, XCD-matched to the GEMM ----
        float* lds = (float*)smem;                       // [32][APITCH]
        float* red = (float*)(smem + 32 * APITCH * 4);   // [32][8]
        const int bb = blockIdx.x - UNITS / 32;
        const int c  = (bb & 7) * 64 + (bb >> 3);        // chunk 0..511
        const float4* src = (const float4*)(in + (size_t)c * 32 * DIM);
        float4* l4 = (float4*)lds;
#pragma unroll
        for (int i = 0; i < 16; i++) {
            const int f = i * 256 + t;                   // float4 id 0..4095
            l4[(f >> 7) * (APITCH / 4) + (f & 127)] = src[f];
        }
        __syncthreads();
        float s = 0.f;
#pragma unroll
        for (int j = 0; j < 8; j++) {
            const int kw = w * 8 + j;
            const float* p = lds + ln * APITCH + kw * 16 + h * 8;
            float4 f0 = *(const float4*)p;
            float4 f1 = *(const float4*)(p + 4);
            s += f0.x * f0.x + f0.y * f0.y + f0.z * f0.z + f0.w * f0.w
               + f1.x * f1.x + f1.y * f1.y + f1.z * f1.z + f1.w * f1.w;
            int lo = __builtin_amdgcn_cvt_pk_fp8_f32(f0.x, f0.y, 0, false);
            lo     = __builtin_amdgcn_cvt_pk_fp8_f32(f0.z, f0.w, lo, true);
            int hi = __builtin_amdgcn_cvt_pk_fp8_f32(f1.x, f1.y, 0, false);
            hi     = __builtin_amdgcn_cvt_pk_fp8_f32(f1.z, f1.w, hi, true);
            *(int2*)(A8f + (((size_t)c * 32 + kw) * 64 + l) * 8) = make_int2(lo, hi);
        }
        red[ln * 8 + w * 2 + h] = s;
        __syncthreads();
        if (t < 32) {
            float a = 0.f;
#pragma unroll
            for (int i = 0; i < 8; i++) a += red[t * 8 + i];
            xsq[c * 32 + t] = a;
        }
    } else {
        // ---- B path: one block per 32-column group ----
        float* lds = (float*)smem;                       // [512][BPITCH]
        float* red = (float*)(smem + 512 * BPITCH * 4);  // [32][8]
        const int nb = blockIdx.x;
        const int n0 = nb * 32;
        const int col = t & 31, kg = t >> 5;
        float s = 0.f;
        for (int i = 0; i < 64; i++) {
            const int k = i * 8 + kg;
            float v = mu[(size_t)k * UNITS + n0 + col];
            s += v * v;
            lds[k * BPITCH + col] = v;
        }
        red[col * 8 + kg] = s;
        __syncthreads();
        if (t < 32) {
            float a = 0.f;
#pragma unroll
            for (int i = 0; i < 8; i++) a += red[t * 8 + i];
            musq[n0 + t] = a;
        }
#pragma unroll
        for (int j = 0; j < 8; j++) {
            const int kw = w * 8 + j;
            const float* p = lds + (kw * 16 + h * 8) * BPITCH + ln;
            float f[8];
#pragma unroll
            for (int i = 0; i < 8; i++) f[i] = p[i * BPITCH];
            int lo = __builtin_amdgcn_cvt_pk_fp8_f32(f[0], f[1], 0, false);
            lo     = __builtin_amdgcn_cvt_pk_fp8_f32(f[2], f[3], lo, true);
            int hi = __builtin_amdgcn_cvt_pk_fp8_f32(f[4], f[5], 0, false);
            hi     = __builtin_amdgcn_cvt_pk_fp8_f32(f[6], f[7], hi, true);
            *(int2*)(B8f + (((size_t)nb * 32 + kw) * 64 + l) * 8) = make_int2(lo, hi);
        }
    }
}

// RBF GEMM v4: 1024 blocks x 256 threads (4 waves), 32 KB LDS -> 4 blocks/CU,
// whole grid co-resident in ONE dispatch round. Block tile 256M x 64N.
// Grid: xcd=b&7, j=b>>3 (0..127), mt=xcd*8+(j&7) (A chunks XCD-local, matches
// prep placement), nt=j>>3 (0..15). Wave w owns rows [m0+w*64, +64) as TWO
// 32M x 64N passes: K-loop then immediate store epilogue, so pass-0 stores
// overlap pass-1 compute, and 4 independent blocks per CU drift to fill the
// write pipe continuously (attacking the phase-bunching that capped v2/v3).
// B8f re-reads (32 KB x 1024 blocks) are XCD-L2-resident. No barriers after
// the B stage. Numerics identical to R4 (same cvt path, same K order).
__global__ __launch_bounds__(256, 4)
void rbf_gemm_kernel(const unsigned char* __restrict__ A8f,
                     const unsigned char* __restrict__ B8f,
                     const float* __restrict__ xsq,
                     const float* __restrict__ musq,
                     float* __restrict__ out) {
    __shared__ __attribute__((aligned(16))) unsigned char Bs[32768]; // 32 KB

    const int t  = threadIdx.x;
    const int l  = t & 63;
    const int w  = t >> 6;          // wave 0..3
    const int ln = l & 31;
    const int h  = l >> 5;

    const int b   = blockIdx.x;     // 0..1023
    const int xcd = b & 7;
    const int j   = b >> 3;         // 0..127
    const int m0  = (xcd * 8 + (j & 7)) * 256;
    const int n0  = (j >> 3) * 64;

    // ---- Stage B-tile (contiguous 32 KB slice of B8f) into LDS ----
    const unsigned char* bsrc = B8f + (size_t)n0 * 512;  // 2 ngs x 16 KB
#pragma unroll
    for (int i = 0; i < 8; i++) {
        const int c = i * 256 + t;                       // 16B chunk 0..2047
        async_copy16(bsrc + c * 16, Bs + c * 16);
    }
    __syncthreads();                                     // only barrier

    const long* BsL = (const long*)Bs;
    const long* Bp  = BsL + l;

    // ---- Two M-passes per wave: 32-row K-loop then store epilogue ----
#pragma unroll
    for (int p = 0; p < 2; p++) {
        const int mbase = m0 + w * 64 + p * 32;
        const long* Af = (const long*)A8f + (size_t)(mbase >> 5) * 2048 + l;

        v16f acc0 = (v16f)0.f, acc1 = (v16f)0.f;
#pragma unroll 4
        for (int kw = 0; kw < 32; kw++) {
            long a  = Af[kw * 64];
            long b0 = Bp[kw * 64];
            long b1 = Bp[2048 + kw * 64];
            acc0 = MFMA_F8(a, b0, acc0);
            acc1 = MFMA_F8(a, b1, acc1);
        }

        // Epilogue for rows [mbase, mbase+32). C/D layout: col = l&31,
        // row = (r&3) + 8*(r>>2) + 4*(l>>5).
        const float xv  = -0.5f * xsq[mbase + ln];       // lane ln: row mbase+ln
        const float mb0 = -0.5f * musq[n0 + ln];
        const float mb1 = -0.5f * musq[n0 + 32 + ln];
        float* obase = out + n0 + ln;
#pragma unroll
        for (int r = 0; r < 16; r++) {
            const int rl = (r & 3) + 8 * (r >> 2) + 4 * h;
            const float xb = __shfl(xv, rl, 64);
            float* orow = obase + (size_t)(mbase + rl) * UNITS;
            __builtin_nontemporal_store(__expf(acc0[r] + xb + mb0), orow);
            __builtin_nontemporal_store(__expf(acc1[r] + xb + mb1), orow + 32);
        }
    }
}

extern "C" void kernel_launch(void* const* d_in, const int* in_sizes, int n_in,
                              void* d_out, int out_size, void* d_ws, size_t ws_size,
                              hipStream_t stream) {
    const float* inputs = (const float*)d_in[0];   // [16384, 512] fp32
    const float* mu     = (const float*)d_in[1];   // [512, 1024] fp32
    float* out = (float*)d_out;                    // [16384, 1024] fp32

    char* ws = (char*)d_ws;
    unsigned char* A8f = (unsigned char*)ws;                           // 8 MiB
    unsigned char* B8f = (unsigned char*)(ws + (size_t)BATCH * DIM);   // 512 KiB
    float* xsq  = (float*)(ws + (size_t)BATCH * DIM + (size_t)UNITS * DIM);
    float* musq = xsq + BATCH;

    prep_kernel<<<UNITS / 32 + BATCH / 32, 256, 0, stream>>>(
        inputs, mu, A8f, B8f, xsq, musq);
    rbf_gemm_kernel<<<1024, 256, 0, stream>>>(A8f, B8f, xsq, musq, out);
}